// Round 4
// baseline (112.331 us; speedup 1.0000x reference)
//
#include <hip/hip_runtime.h>
#include <hip/hip_bf16.h>

typedef float f32x4 __attribute__((ext_vector_type(4)));
typedef __bf16 bf16x8 __attribute__((ext_vector_type(8)));

#define NC 4096
#define ND 1024
#define EPSF 1e-10f
#define NT 16  // K-tiles of BK=64

__device__ __forceinline__ unsigned short f2bf(float f) {
  unsigned int u = __float_as_uint(f);
  return (unsigned short)((u + 0x7fffu + ((u >> 16) & 1u)) >> 16);
}

// ---------------- fp32 -> bf16 convert + row norms/sums; last block = mask ----------------
__global__ void convert_kernel(const float* __restrict__ F, const float* __restrict__ P,
                               unsigned short* __restrict__ Fb, unsigned short* __restrict__ Pb,
                               float* __restrict__ f2, float* __restrict__ p2,
                               float* __restrict__ psum,
                               const int* __restrict__ ann, int n_ann,
                               float* __restrict__ counts, float* __restrict__ accum) {
  int bid = blockIdx.x;
  int tid = threadIdx.x;
  if (bid == 2 * NC) {  // fused mask/zero block (no atomics: LDS bitmap)
    __shared__ unsigned char mark[NC];
    for (int i = tid; i < NC; i += 256) mark[i] = 0;
    __syncthreads();
    for (int t = tid; t < n_ann; t += 256) {
      int idx = ann[t * 5 + 4];
      if (idx >= 0 && idx < NC) mark[idx] = 1;  // benign race: all write 1
    }
    __syncthreads();
    for (int i = tid; i < NC; i += 256) counts[i] = (float)mark[i];
    if (tid < 8) accum[tid] = 0.f;   // re-zero every call (graph replay)
    return;
  }
  bool isP = bid >= NC;
  int row = isP ? bid - NC : bid;
  const float* src = (isP ? P : F) + (size_t)row * ND;
  unsigned short* dst = (isP ? Pb : Fb) + (size_t)row * ND;
  float4 v = *reinterpret_cast<const float4*>(src + tid * 4);
  ushort4 o;
  o.x = f2bf(v.x); o.y = f2bf(v.y); o.z = f2bf(v.z); o.w = f2bf(v.w);
  *reinterpret_cast<ushort4*>(dst + tid * 4) = o;
  float sq = v.x * v.x + v.y * v.y + v.z * v.z + v.w * v.w;
  float sm = v.x + v.y + v.z + v.w;
  #pragma unroll
  for (int off = 32; off; off >>= 1) {
    sq += __shfl_down(sq, off);
    sm += __shfl_down(sm, off);
  }
  __shared__ float rs[4], rm[4];
  int wid = tid >> 6, lane = tid & 63;
  if (lane == 0) { rs[wid] = sq; rm[wid] = sm; }
  __syncthreads();
  if (tid == 0) {
    float tsq = rs[0] + rs[1] + rs[2] + rs[3];
    float tsm = rm[0] + rm[1] + rm[2] + rm[3];
    if (isP) { p2[row] = tsq; psum[row] = tsm; }
    else     { f2[row] = tsq; }
  }
}

// ---------------- fused 256x128 2-phase GEMM + loss reduction ----------------
#define GLDS(gsrc, ldst)                                                     \
  __builtin_amdgcn_global_load_lds(                                          \
      (__attribute__((address_space(1))) void*)(void*)(gsrc),                \
      (__attribute__((address_space(3))) void*)(void*)(ldst), 16, 0, 0)

#define FENCE() asm volatile("" ::: "memory")
#define BAR()  do { FENCE(); __builtin_amdgcn_s_barrier(); FENCE(); } while (0)
#define VMCNT0() asm volatile("s_waitcnt vmcnt(0)" ::: "memory")
#define LGKMCNT0() asm volatile("s_waitcnt lgkmcnt(0)" ::: "memory")

// Stage all three regions (A0: F rows 0-127, A1: F rows 128-255, B: P rows)
// of K-tile kt. Linear LDS dest (global_load_lds constraint), inverse-
// swizzled global source; ds_read applies the matching XOR (rule 21).
#define STAGEALL(kt)                                                          \
  do {                                                                        \
    _Pragma("unroll")                                                         \
    for (int _c = 0; _c < 2; ++_c) {                                          \
      size_t _col = (size_t)(kt) * 64 + scol[_c];                             \
      GLDS(Fb + arow0 + (size_t)srow[_c] * ND + _col, &lds[0][ldso[_c]]);     \
      GLDS(Fb + arow0 + (size_t)(128 + srow[_c]) * ND + _col,                 \
           &lds[1][ldso[_c]]);                                                \
      GLDS(Pb + brow0 + (size_t)srow[_c] * ND + _col, &lds[2][ldso[_c]]);     \
    }                                                                         \
  } while (0)

__global__ __launch_bounds__(512, 4)   // 4 waves/EU = 2 blocks/CU target
void gemm_loss_kernel(const unsigned short* __restrict__ Fb,
                      const unsigned short* __restrict__ Pb,
                      const float* __restrict__ f2, const float* __restrict__ p2,
                      const float* __restrict__ counts, const float* __restrict__ psum,
                      float* accum) {
  // A0, A1, B regions: 128 rows x 64 bf16 (128 B/row) each = 48 KiB total
  __shared__ __attribute__((aligned(16))) unsigned short lds[3][8192];
  __shared__ float redI[8], redE[8];

  // XCD-bijective swizzle: 512 wgs, 8 XCDs, 64 contiguous tiles each
  const int wg = (blockIdx.x & 7) * 64 + (blockIdx.x >> 3);
  const int bi = wg >> 5, bj = wg & 31;   // bi: 16 row-tiles of 256; bj: 32 col-tiles of 128

  const int tid = threadIdx.x;
  const int lane = tid & 63, wid = tid >> 6;
  const int wrm = wid >> 1, wn = wid & 1;  // 4 (M) x 2 (N) wave grid; 64x64 per wave
  const int lo = lane & 15, hi = lane >> 4;

  // staging chunk geometry: per region 1024 chunks of 16 B, 2 per thread
  int srow[2], scol[2], ldso[2];
  #pragma unroll
  for (int c = 0; c < 2; ++c) {
    int idx = c * 512 + tid;
    srow[c] = idx >> 3;                        // row 0..127
    scol[c] = ((idx & 7) ^ (srow[c] & 7)) * 8; // swizzled k-start (elements)
    ldso[c] = idx * 8;                         // ushort offset in region
  }
  const size_t arow0 = (size_t)(bi * 256) * ND;
  const size_t brow0 = (size_t)(bj * 128) * ND;

  bf16x8 av[8], bv[8];
  f32x4 acc[4][4];
  f32x4 zero = {0.f, 0.f, 0.f, 0.f};
  #pragma unroll
  for (int m = 0; m < 4; ++m)
    #pragma unroll
    for (int n = 0; n < 4; ++n) acc[m][n] = zero;

  // Prologue: stage K-tile 0, drain, barrier.
  STAGEALL(0);
  VMCNT0();
  BAR();

  // 2-barrier K-loop (T3 minimum): read-all -> lgkmcnt(0) -> BAR ->
  // stage next tile into just-freed regions -> 32-MFMA cluster ->
  // vmcnt(0) -> BAR. Stage-issue precedes MFMA so HBM/L2 latency hides
  // under compute; co-resident block covers the drains.
  #pragma unroll 1
  for (int kt = 0; kt < NT; ++kt) {
    // read all 16 fragments for this tile
    {
      const char* ab = (const char*)&lds[wrm >> 1][0];
      #pragma unroll
      for (int m = 0; m < 4; ++m)
        #pragma unroll
        for (int k = 0; k < 2; ++k) {
          int r = (wrm & 1) * 64 + m * 16 + lo;
          int kb = k * 64 + hi * 16;
          av[m * 2 + k] = *(const bf16x8*)(ab + r * 128 + (kb ^ ((r & 7) << 4)));
        }
      const char* bb = (const char*)&lds[2][0];
      #pragma unroll
      for (int n = 0; n < 4; ++n)
        #pragma unroll
        for (int k = 0; k < 2; ++k) {
          int r = wn * 64 + n * 16 + lo;
          int kb = k * 64 + hi * 16;
          bv[n * 2 + k] = *(const bf16x8*)(bb + r * 128 + (kb ^ ((r & 7) << 4)));
        }
    }
    LGKMCNT0();                        // all LDS reads of this tile complete
    __builtin_amdgcn_sched_barrier(0); // rule 18: pin the wait
    BAR();                             // every wave done reading -> regions free
    if (kt + 1 < NT) STAGEALL(kt + 1); // 6 global_load_lds into freed regions
    __builtin_amdgcn_s_setprio(1);
    #pragma unroll
    for (int m = 0; m < 4; ++m)
      #pragma unroll
      for (int n = 0; n < 4; ++n)
        #pragma unroll
        for (int k = 0; k < 2; ++k)
          acc[m][n] = __builtin_amdgcn_mfma_f32_16x16x32_bf16(
              av[m * 2 + k], bv[n * 2 + k], acc[m][n], 0, 0, 0);
    __builtin_amdgcn_s_setprio(0);
    VMCNT0();                          // this wave's stages landed
    BAR();                             // all waves' stages landed -> safe to read
  }

  // Epilogue: per-element msd -> intra (diag) / inter (off-diag) partials.
  // C/D layout (m89-verified): col = lane&15, row = (lane>>4)*4 + reg.
  float intra_l = 0.f, inter_l = 0.f;
  const int gi0 = bi * 256 + wrm * 64 + hi * 4;
  const int gj0 = bj * 128 + wn * 64 + lo;
  float f2i[16];
  int mi[16];
  #pragma unroll
  for (int m = 0; m < 4; ++m)
    #pragma unroll
    for (int r = 0; r < 4; ++r) {
      int gi = gi0 + m * 16 + r;
      f2i[m * 4 + r] = f2[gi];
      mi[m * 4 + r] = counts[gi] > 0.f;
    }
  #pragma unroll
  for (int n = 0; n < 4; ++n) {
    int gj = gj0 + n * 16;
    float p2j = p2[gj];
    bool mj = psum[gj] != 0.f;
    if (mj) {
      #pragma unroll
      for (int m = 0; m < 4; ++m) {
        #pragma unroll
        for (int r = 0; r < 4; ++r) {
          if (!mi[m * 4 + r]) continue;
          int gi = gi0 + m * 16 + r;
          float cij = acc[m][n][r];
          float msd = fmaxf(f2i[m * 4 + r] + p2j - 2.f * cij, 0.f) * (1.f / 1024.f);
          if (gi == gj) {
            intra_l += msd;                 // diagonal: intra
          } else if (msd < 1.0f) {          // inter term nonzero only if sqrt(msd)<1
            float s = sqrtf(fmaxf(msd, 1e-12f));
            float e = 1.f - s;
            float e2 = e * e;
            inter_l += e2 * e2;             // (e/M)^2 * max(e,0)^2, M=1
          }
        }
      }
    }
  }
  #pragma unroll
  for (int off = 32; off; off >>= 1) {
    intra_l += __shfl_down(intra_l, off);
    inter_l += __shfl_down(inter_l, off);
  }
  if (lane == 0) { redI[wid] = intra_l; redE[wid] = inter_l; }
  __syncthreads();
  if (tid == 0) {
    float si = 0.f, se = 0.f;
    #pragma unroll
    for (int w = 0; w < 8; ++w) { si += redI[w]; se += redE[w]; }
    atomicAdd(&accum[0], si);
    atomicAdd(&accum[1], se);
  }
}

// ---------------- mask counts + finalize (fused) ----------------
__global__ void finalize_kernel(const float* __restrict__ counts,
                                const float* __restrict__ psum,
                                const float* __restrict__ accum,
                                float* __restrict__ out) {
  int tid = threadIdx.x;
  int ni = 0, nj = 0, nd = 0;
  for (int i = tid; i < NC; i += 256) {
    int mi = counts[i] > 0.f;
    int mj = psum[i] != 0.f;
    ni += mi; nj += mj; nd += (mi & mj);
  }
  #pragma unroll
  for (int off = 32; off; off >>= 1) {
    ni += __shfl_down(ni, off);
    nj += __shfl_down(nj, off);
    nd += __shfl_down(nd, off);
  }
  __shared__ int r0[4], r1[4], r2[4];
  int wid = tid >> 6, lane = tid & 63;
  if (lane == 0) { r0[wid] = ni; r1[wid] = nj; r2[wid] = nd; }
  __syncthreads();
  if (tid == 0) {
    float fni = (float)(r0[0] + r0[1] + r0[2] + r0[3]);
    float fnj = (float)(r1[0] + r1[1] + r1[2] + r1[3]);
    float fnd = (float)(r2[0] + r2[1] + r2[2] + r2[3]);
    out[0] = accum[0] / (fnd + EPSF);
    out[1] = accum[1] / (fni * fnj - fnd + EPSF);
  }
}

extern "C" void kernel_launch(void* const* d_in, const int* in_sizes, int n_in,
                              void* d_out, int out_size, void* d_ws, size_t ws_size,
                              hipStream_t stream) {
  const float* F = (const float*)d_in[0];
  const float* P = (const float*)d_in[1];
  const int* ann = (const int*)d_in[2];
  int n_ann = in_sizes[2] / 5;

  char* ws = (char*)d_ws;
  unsigned short* Fb = (unsigned short*)ws;                          // 8 MB
  unsigned short* Pb = (unsigned short*)(ws + (size_t)NC * ND * 2);  // 8 MB
  float* f2     = (float*)(ws + (size_t)NC * ND * 4);
  float* p2     = f2 + NC;
  float* psum   = p2 + NC;
  float* counts = psum + NC;
  float* accum  = counts + NC;  // [0]=intra_sum [1]=inter_sum

  float* out = (float*)d_out;

  convert_kernel<<<2 * NC + 1, 256, 0, stream>>>(F, P, Fb, Pb, f2, p2, psum,
                                                 ann, n_ann, counts, accum);
  gemm_loss_kernel<<<(NC / 256) * (NC / 128), 512, 0, stream>>>(Fb, Pb, f2, p2, counts, psum, accum);
  finalize_kernel<<<1, 256, 0, stream>>>(counts, psum, accum, out);
}

// Round 5
// 56.572 us; speedup vs baseline: 1.9856x; 1.9856x over previous
//
#include <hip/hip_runtime.h>
#include <hip/hip_bf16.h>

typedef float f32x4 __attribute__((ext_vector_type(4)));
typedef int   i32x4 __attribute__((ext_vector_type(4)));
typedef int   i32x8 __attribute__((ext_vector_type(8)));

#define NC 4096
#define ND 1024
#define EPSF 1e-10f
#define NT 8        // K-tiles of BK=128 (fp8)
#define SCALE1 127  // E8M0 exponent byte for 2^0

// ---------------- fp32 -> fp8 e4m3 convert + row norms/sums; last block = mask ----------------
__global__ void convert_kernel(const float* __restrict__ F, const float* __restrict__ P,
                               unsigned char* __restrict__ Fb, unsigned char* __restrict__ Pb,
                               float* __restrict__ f2, float* __restrict__ p2,
                               float* __restrict__ psum,
                               const int* __restrict__ ann, int n_ann,
                               float* __restrict__ counts, float* __restrict__ accum) {
  int bid = blockIdx.x;
  int tid = threadIdx.x;
  if (bid == 2 * NC) {  // fused mask/zero block (no atomics: LDS bitmap)
    __shared__ unsigned char mark[NC];
    for (int i = tid; i < NC; i += 256) mark[i] = 0;
    __syncthreads();
    for (int t = tid; t < n_ann; t += 256) {
      int idx = ann[t * 5 + 4];
      if (idx >= 0 && idx < NC) mark[idx] = 1;  // benign race: all write 1
    }
    __syncthreads();
    for (int i = tid; i < NC; i += 256) counts[i] = (float)mark[i];
    if (tid < 8) accum[tid] = 0.f;   // re-zero every call (graph replay)
    return;
  }
  bool isP = bid >= NC;
  int row = isP ? bid - NC : bid;
  const float* src = (isP ? P : F) + (size_t)row * ND;
  unsigned char* dst = (isP ? Pb : Fb) + (size_t)row * ND;
  float4 v = *reinterpret_cast<const float4*>(src + tid * 4);
  int pk = __builtin_amdgcn_cvt_pk_fp8_f32(v.x, v.y, 0, false);   // bytes 0,1
  pk = __builtin_amdgcn_cvt_pk_fp8_f32(v.z, v.w, pk, true);       // bytes 2,3
  *reinterpret_cast<int*>(dst + tid * 4) = pk;
  float sq = v.x * v.x + v.y * v.y + v.z * v.z + v.w * v.w;
  float sm = v.x + v.y + v.z + v.w;
  #pragma unroll
  for (int off = 32; off; off >>= 1) {
    sq += __shfl_down(sq, off);
    sm += __shfl_down(sm, off);
  }
  __shared__ float rs[4], rm[4];
  int wid = tid >> 6, lane = tid & 63;
  if (lane == 0) { rs[wid] = sq; rm[wid] = sm; }
  __syncthreads();
  if (tid == 0) {
    float tsq = rs[0] + rs[1] + rs[2] + rs[3];
    float tsm = rm[0] + rm[1] + rm[2] + rm[3];
    if (isP) { p2[row] = tsq; psum[row] = tsm; }
    else     { f2[row] = tsq; }
  }
}

// ---------------- fused 128x256 8-phase MX-fp8 GEMM + loss reduction ----------------
#define GLDS(gsrc, ldst)                                                     \
  __builtin_amdgcn_global_load_lds(                                          \
      (__attribute__((address_space(1))) void*)(void*)(gsrc),                \
      (__attribute__((address_space(3))) void*)(void*)(ldst), 16, 0, 0)

#define FENCE() asm volatile("" ::: "memory")
#define BAR()  do { FENCE(); __builtin_amdgcn_s_barrier(); FENCE(); } while (0)
#define VMCNT4() asm volatile("s_waitcnt vmcnt(4)" ::: "memory")

// LDS layout per dbuf (48 KiB): A0 rows 0-63 @0, A1 rows 64-127 @8192,
// B0 cols 0-127 @16384, B1 cols 128-255 @32768. Rows are 128 B (K=128 fp8).
// Linear LDS dest (global_load_lds), inverse-swizzled global source;
// ds_read applies the matching XOR (rule 21: both-sides-or-neither).

// Stage A-half h (64 rows) of K-tile kt into dbuf d: 1 load/thread.
#define STAGEA(d, h, kt)                                                      \
  GLDS(Fb + abase + (size_t)((h) * 64 + sra) * ND + (size_t)(kt) * 128 + sca, \
       &lds[d][(h) * 8192 + lao])

// Stage B-half h (128 rows) of K-tile kt into dbuf d: 2 loads/thread.
#define STAGEB(d, h, kt)                                                      \
  do {                                                                        \
    _Pragma("unroll")                                                         \
    for (int _c = 0; _c < 2; ++_c)                                            \
      GLDS(Pb + bbase + (size_t)((h) * 128 + srb[_c]) * ND +                  \
               (size_t)(kt) * 128 + scb[_c],                                  \
           &lds[d][16384 + (h) * 16384 + lbo[_c]]);                           \
  } while (0)

// Load av[2] = m-frags QM*2, QM*2+1 from the wave's A region.
#define LDA(DB, QM)                                                           \
  do {                                                                        \
    const unsigned char* _b = &lds[DB][wr * 8192];                            \
    _Pragma("unroll")                                                         \
    for (int _f = 0; _f < 2; ++_f) {                                          \
      int _r = (QM) * 32 + _f * 16 + lo;                                      \
      int _x = (_r & 7) << 4;                                                 \
      i32x4 _l0 = *(const i32x4*)(_b + _r * 128 + ((hi * 32) ^ _x));          \
      i32x4 _l1 = *(const i32x4*)(_b + _r * 128 + ((hi * 32 + 16) ^ _x));     \
      av[_f][0] = _l0[0]; av[_f][1] = _l0[1];                                 \
      av[_f][2] = _l0[2]; av[_f][3] = _l0[3];                                 \
      av[_f][4] = _l1[0]; av[_f][5] = _l1[1];                                 \
      av[_f][6] = _l1[2]; av[_f][7] = _l1[3];                                 \
    }                                                                         \
  } while (0)

// Load BV[2] = n-frags QN*2, QN*2+1 from the wave's B region.
#define LDB(DB, QN, BV)                                                       \
  do {                                                                        \
    const unsigned char* _b = &lds[DB][16384 + (wc >> 1) * 16384];            \
    _Pragma("unroll")                                                         \
    for (int _g = 0; _g < 2; ++_g) {                                          \
      int _r = (wc & 1) * 64 + (QN) * 32 + _g * 16 + lo;                      \
      int _x = (_r & 7) << 4;                                                 \
      i32x4 _l0 = *(const i32x4*)(_b + _r * 128 + ((hi * 32) ^ _x));          \
      i32x4 _l1 = *(const i32x4*)(_b + _r * 128 + ((hi * 32 + 16) ^ _x));     \
      BV[_g][0] = _l0[0]; BV[_g][1] = _l0[1];                                 \
      BV[_g][2] = _l0[2]; BV[_g][3] = _l0[3];                                 \
      BV[_g][4] = _l1[0]; BV[_g][5] = _l1[1];                                 \
      BV[_g][6] = _l1[2]; BV[_g][7] = _l1[3];                                 \
    }                                                                         \
  } while (0)

#define MMA(QM, QN, BV)                                                       \
  do {                                                                        \
    __builtin_amdgcn_s_setprio(1);                                            \
    _Pragma("unroll")                                                         \
    for (int _f = 0; _f < 2; ++_f)                                            \
      _Pragma("unroll")                                                       \
      for (int _g = 0; _g < 2; ++_g)                                          \
        acc[(QM) * 2 + _f][(QN) * 2 + _g] =                                   \
            __builtin_amdgcn_mfma_scale_f32_16x16x128_f8f6f4(                 \
                av[_f], BV[_g], acc[(QM) * 2 + _f][(QN) * 2 + _g],            \
                0 /*A=fp8*/, 0 /*B=fp8*/, 0, SCALE1, 0, SCALE1);              \
    __builtin_amdgcn_s_setprio(0);                                            \
  } while (0)

__global__ __launch_bounds__(512, 2)
void gemm_loss_kernel(const unsigned char* __restrict__ Fb,
                      const unsigned char* __restrict__ Pb,
                      const float* __restrict__ f2, const float* __restrict__ p2,
                      const float* __restrict__ counts, const float* __restrict__ psum,
                      float* accum) {
  __shared__ __attribute__((aligned(16))) unsigned char lds[2][49152];  // 96 KiB
  __shared__ float redI[8], redE[8];

  // XCD-bijective swizzle: 512 wgs, 8 XCDs, 64 contiguous tiles each
  const int wg = (blockIdx.x & 7) * 64 + (blockIdx.x >> 3);
  const int bi = wg >> 4, bj = wg & 15;  // bi: 32 row-tiles of 128; bj: 16 col-tiles of 256

  const int tid = threadIdx.x;
  const int lane = tid & 63, wid = tid >> 6;
  const int wr = wid >> 2, wc = wid & 3;  // 2 (M) x 4 (N) wave grid; 64x64 per wave
  const int lo = lane & 15, hi = lane >> 4;

  // A staging: 512 chunks of 16 B per half (64 rows x 8 slots), 1/thread
  const int sra = tid >> 3;
  const int sca = ((tid & 7) ^ (sra & 7)) * 16;
  const int lao = tid * 16;
  // B staging: 1024 chunks per half (128 rows x 8 slots), 2/thread
  int srb[2], scb[2], lbo[2];
  #pragma unroll
  for (int c = 0; c < 2; ++c) {
    int idx = c * 512 + tid;
    srb[c] = idx >> 3;
    scb[c] = ((idx & 7) ^ (srb[c] & 7)) * 16;
    lbo[c] = idx * 16;
  }
  const size_t abase = (size_t)(bi * 128) * ND;
  const size_t bbase = (size_t)(bj * 256) * ND;

  i32x8 av[2], bv0[2], bv1[2];
  f32x4 acc[4][4];
  f32x4 zero = {0.f, 0.f, 0.f, 0.f};
  #pragma unroll
  for (int m = 0; m < 4; ++m)
    #pragma unroll
    for (int n = 0; n < 4; ++n) acc[m][n] = zero;

  // Prologue: K-tile 0 fully into dbuf0 (6 loads); B-halves of K-tile 1
  // into dbuf1 (4 loads). A-halves of odd tiles staged at P1/P2.
  STAGEA(0, 0, 0); STAGEA(0, 1, 0); STAGEB(0, 0, 0); STAGEB(0, 1, 0);
  STAGEB(1, 0, 1); STAGEB(1, 1, 1);
  VMCNT4();  // dbuf0's 6 landed; dbuf1's 4 B-loads may stay in flight
  BAR();

  // 4 iterations, 2 K-tiles each. Even K-tile in dbuf0 (P1-P4), odd in
  // dbuf1 (P5-P8). A-halves last read P3 (staged P5/P6 for next); B-halves
  // last read P2/P6 (staged P3/P4 and P7/P8). VMCNT4 at P4/P8 = exactly
  // the 4 loads issued after the stage that must have landed.
  #pragma unroll 1
  for (int it = 0; it < NT / 2; ++it) {
    const int k1 = 2 * it + 1, kn0 = 2 * it + 2, kn1 = 2 * it + 3;
    // P1
    LDA(0, 0); LDB(0, 0, bv0);
    STAGEA(1, 0, k1);
    BAR(); MMA(0, 0, bv0); BAR();
    // P2
    LDB(0, 1, bv1);
    STAGEA(1, 1, k1);
    BAR(); MMA(0, 1, bv1); BAR();
    // P3
    LDA(0, 1);
    if (kn0 < NT) STAGEB(0, 0, kn0);
    BAR(); MMA(1, 0, bv0); BAR();
    // P4
    if (kn0 < NT) STAGEB(0, 1, kn0);
    VMCNT4();                          // dbuf1 (k1) fully landed
    BAR(); MMA(1, 1, bv1); BAR();
    // P5
    LDA(1, 0); LDB(1, 0, bv0);
    if (kn0 < NT) STAGEA(0, 0, kn0);
    BAR(); MMA(0, 0, bv0); BAR();
    // P6
    LDB(1, 1, bv1);
    if (kn0 < NT) STAGEA(0, 1, kn0);
    BAR(); MMA(0, 1, bv1); BAR();
    // P7
    LDA(1, 1);
    if (kn1 < NT) STAGEB(1, 0, kn1);
    BAR(); MMA(1, 0, bv0); BAR();
    // P8
    if (kn1 < NT) STAGEB(1, 1, kn1);
    VMCNT4();                          // dbuf0 (kn0) fully landed
    BAR(); MMA(1, 1, bv1); BAR();
  }

  // Epilogue: per-element msd -> intra (diag) / inter (off-diag) partials.
  // C/D layout (shape-determined, dtype-independent): col=lane&15, row=(lane>>4)*4+reg.
  float intra_l = 0.f, inter_l = 0.f;
  const int gi0 = bi * 128 + wr * 64 + hi * 4;
  const int gj0 = bj * 256 + wc * 64 + lo;
  float f2i[16];
  int mi[16];
  #pragma unroll
  for (int m = 0; m < 4; ++m)
    #pragma unroll
    for (int r = 0; r < 4; ++r) {
      int gi = gi0 + m * 16 + r;
      f2i[m * 4 + r] = f2[gi];
      mi[m * 4 + r] = counts[gi] > 0.f;
    }
  #pragma unroll
  for (int n = 0; n < 4; ++n) {
    int gj = gj0 + n * 16;
    float p2j = p2[gj];
    bool mj = psum[gj] != 0.f;
    if (mj) {
      #pragma unroll
      for (int m = 0; m < 4; ++m) {
        #pragma unroll
        for (int r = 0; r < 4; ++r) {
          if (!mi[m * 4 + r]) continue;
          int gi = gi0 + m * 16 + r;
          float cij = acc[m][n][r];
          float msd = fmaxf(f2i[m * 4 + r] + p2j - 2.f * cij, 0.f) * (1.f / 1024.f);
          if (gi == gj) {
            intra_l += msd;                 // diagonal: intra
          } else if (msd < 1.0f) {          // inter term nonzero only if sqrt(msd)<1
            float s = sqrtf(fmaxf(msd, 1e-12f));
            float e = 1.f - s;
            float e2 = e * e;
            inter_l += e2 * e2;             // (e/M)^2 * max(e,0)^2, M=1
          }
        }
      }
    }
  }
  #pragma unroll
  for (int off = 32; off; off >>= 1) {
    intra_l += __shfl_down(intra_l, off);
    inter_l += __shfl_down(inter_l, off);
  }
  if (lane == 0) { redI[wid] = intra_l; redE[wid] = inter_l; }
  __syncthreads();
  if (tid == 0) {
    float si = 0.f, se = 0.f;
    #pragma unroll
    for (int w = 0; w < 8; ++w) { si += redI[w]; se += redE[w]; }
    atomicAdd(&accum[0], si);
    atomicAdd(&accum[1], se);
  }
}

// ---------------- mask counts + finalize (fused) ----------------
__global__ void finalize_kernel(const float* __restrict__ counts,
                                const float* __restrict__ psum,
                                const float* __restrict__ accum,
                                float* __restrict__ out) {
  int tid = threadIdx.x;
  int ni = 0, nj = 0, nd = 0;
  for (int i = tid; i < NC; i += 256) {
    int mi = counts[i] > 0.f;
    int mj = psum[i] != 0.f;
    ni += mi; nj += mj; nd += (mi & mj);
  }
  #pragma unroll
  for (int off = 32; off; off >>= 1) {
    ni += __shfl_down(ni, off);
    nj += __shfl_down(nj, off);
    nd += __shfl_down(nd, off);
  }
  __shared__ int r0[4], r1[4], r2[4];
  int wid = tid >> 6, lane = tid & 63;
  if (lane == 0) { r0[wid] = ni; r1[wid] = nj; r2[wid] = nd; }
  __syncthreads();
  if (tid == 0) {
    float fni = (float)(r0[0] + r0[1] + r0[2] + r0[3]);
    float fnj = (float)(r1[0] + r1[1] + r1[2] + r1[3]);
    float fnd = (float)(r2[0] + r2[1] + r2[2] + r2[3]);
    out[0] = accum[0] / (fnd + EPSF);
    out[1] = accum[1] / (fni * fnj - fnd + EPSF);
  }
}

extern "C" void kernel_launch(void* const* d_in, const int* in_sizes, int n_in,
                              void* d_out, int out_size, void* d_ws, size_t ws_size,
                              hipStream_t stream) {
  const float* F = (const float*)d_in[0];
  const float* P = (const float*)d_in[1];
  const int* ann = (const int*)d_in[2];
  int n_ann = in_sizes[2] / 5;

  char* ws = (char*)d_ws;
  unsigned char* Fb = (unsigned char*)ws;                          // 4 MB
  unsigned char* Pb = (unsigned char*)(ws + (size_t)NC * ND);      // 4 MB
  float* f2     = (float*)(ws + (size_t)NC * ND * 2);
  float* p2     = f2 + NC;
  float* psum   = p2 + NC;
  float* counts = psum + NC;
  float* accum  = counts + NC;  // [0]=intra_sum [1]=inter_sum

  float* out = (float*)d_out;

  convert_kernel<<<2 * NC + 1, 256, 0, stream>>>(F, P, Fb, Pb, f2, p2, psum,
                                                 ann, n_ann, counts, accum);
  gemm_loss_kernel<<<(NC / 128) * (NC / 256), 512, 0, stream>>>(Fb, Pb, f2, p2, counts, psum, accum);
  finalize_kernel<<<1, 256, 0, stream>>>(counts, psum, accum, out);
}